// Round 4
// baseline (232.626 us; speedup 1.0000x reference)
//
#include <hip/hip_runtime.h>
#include <hip/hip_bf16.h>

// MSAttention on MI355X. R14:
//  - k_dwconv + k_mm_pw FUSED into k_fused (one launch per scale, 3 total; tmp buffer deleted).
//    Per block (64-token n-tile, one b): stage 4 input image rows x 128 c into LDS bf16 (Fin,
//    with s>=2 residual add), compute 3x3 depthwise in-LDS (c wave-uniform, lane=(row,col) ->
//    conflict-free), write straight into the pw-GEMM Bs fragments (both K=64 halves), then the
//    R13 mm_pw MFMA loop + BN2 epilogue, with As staged into the Fin region (union, Fin dead).
//    Removes 3 launches + 24 MB tmp round-trip + k_dwconv time; middle was launch/latency-bound
//    (mm_pw at 128 blocks = 1 wave/SIMD).
//  - k_attn etc. identical to R13 (197.1 us total, absmax 0.150; k_attn ~37 us est).
// ws layout (32 MB):
//   @0   Y   f32 [8][512][1024] 16 MB (mm_in -> fused convs -> prep)  then Ob bf16 [8192][512] 8 MB
//   @16  Vp bf16 [128][8jt][8sub][64lane][8] 8 MB (prep)
//   @24  Qt bf16 [128][1024][32] 8 MB (prep)

#define DIMM 512
#define NTOK 1024
#define CC   128
#define DD   32
#define BB   8
#define EPSB 1e-5f
#define SCALE_ATT 0.17677669529663687f   // 32^-0.5
#define K2EXP (SCALE_ATT * 1.4426950408889634f)  // scale * log2(e), folded into exp2
#define TJ 128

typedef __attribute__((ext_vector_type(8))) short short8;
typedef __attribute__((ext_vector_type(4))) float f32x4;

__device__ __forceinline__ unsigned short f2bf(float f) {
    unsigned int x = __float_as_uint(f);
    unsigned int r = x + 0x7fffu + ((x >> 16) & 1u);   // RNE, finite inputs
    return (unsigned short)(r >> 16);
}
__device__ __forceinline__ unsigned int f2bf2(float lo, float hi) {
    return (unsigned int)f2bf(lo) | ((unsigned int)f2bf(hi) << 16);
}
__device__ __forceinline__ float bf2f(unsigned short u) {
    return __uint_as_float(((unsigned int)u) << 16);
}

// ---------------- K1: inconv GEMM (MFMA bf16, inline f32->bf16 staging) + BN1 ----------------
__global__ __launch_bounds__(256) void k_mm_in(
    const float* __restrict__ w_in,   // [512][512]
    const float* __restrict__ x,      // [8192][512]
    const float* __restrict__ g1, const float* __restrict__ b1,
    const float* __restrict__ m1, const float* __restrict__ v1,
    float* __restrict__ Y)
{
    __shared__ __align__(16) unsigned short As[128][72];
    __shared__ __align__(16) unsigned short Bs[128][72];
    const int r0 = blockIdx.x * 128;
    const int o0 = blockIdx.y * 128;
    const int b  = r0 >> 10, nloc0 = r0 & 1023;
    const int t = threadIdx.x, wid = t >> 6, lane = t & 63;
    const int l16 = lane & 15, quad = lane >> 4;
    const int wm = (wid >> 1) * 64, wn = (wid & 1) * 64;

    f32x4 acc[4][4];
#pragma unroll
    for (int i = 0; i < 4; i++)
#pragma unroll
        for (int j = 0; j < 4; j++) acc[i][j] = (f32x4){0.f, 0.f, 0.f, 0.f};

    for (int k0 = 0; k0 < DIMM; k0 += 64) {
        __syncthreads();
#pragma unroll
        for (int it = 0; it < 8; it++) {
            int flat = it * 256 + t;
            int row = flat >> 4, c4 = flat & 15;
            float4 w4 = *(const float4*)&w_in[(size_t)(o0 + row) * DIMM + k0 + c4 * 4];
            *(uint2*)&As[row][c4 * 4] = make_uint2(f2bf2(w4.x, w4.y), f2bf2(w4.z, w4.w));
            float4 x4 = *(const float4*)&x[(size_t)(r0 + row) * DIMM + k0 + c4 * 4];
            *(uint2*)&Bs[row][c4 * 4] = make_uint2(f2bf2(x4.x, x4.y), f2bf2(x4.z, x4.w));
        }
        __syncthreads();
#pragma unroll
        for (int kk = 0; kk < 2; kk++) {
            short8 af[4], bf_[4];
#pragma unroll
            for (int i = 0; i < 4; i++) af[i]  = *(const short8*)&As[wm + i * 16 + l16][kk * 32 + quad * 8];
#pragma unroll
            for (int j = 0; j < 4; j++) bf_[j] = *(const short8*)&Bs[wn + j * 16 + l16][kk * 32 + quad * 8];
#pragma unroll
            for (int i = 0; i < 4; i++)
#pragma unroll
                for (int j = 0; j < 4; j++)
                    acc[i][j] = __builtin_amdgcn_mfma_f32_16x16x32_bf16(af[i], bf_[j], acc[i][j], 0, 0, 0);
        }
    }
#pragma unroll
    for (int i = 0; i < 4; i++)
#pragma unroll
        for (int r = 0; r < 4; r++) {
            int o = o0 + wm + i * 16 + quad * 4 + r;
            float inv  = g1[o] / sqrtf(v1[o] + EPSB);
            float beta = b1[o] - m1[o] * inv;
#pragma unroll
            for (int j = 0; j < 4; j++) {
                int n = nloc0 + wn + j * 16 + l16;
                Y[((size_t)b * DIMM + o) * NTOK + n] = acc[i][j][r] * inv + beta;
            }
        }
}

// ---------------- K2: fused depthwise 3x3 + pointwise 1x1 MFMA + BN2 (one launch per s) -------
// Block: (n-tile 64 = 2 image rows, b). grid (16, 8). 256 thr.
// LDS: Fin bf16 [128c][4row][32col] 32KB (union w/ As [128][72] 18.4KB) | Bs [2][64][72] 18.4KB
//      | Wdw f32 [128*9] 4.6KB. Total 55.8 KB static -> 2 blocks/CU.
#define FU_OFF_BS  32768
#define FU_OFF_WDW (32768 + 2 * 64 * 72 * 2)
#define FU_SMEM    (FU_OFF_WDW + 128 * 9 * 4)

__global__ __launch_bounds__(256) void k_fused(
    const float* __restrict__ Y_in,       // Y (read slices s, s-1)
    const float* __restrict__ w_dw,       // [128][9]
    const float* __restrict__ w_pw,       // [128][128]
    const float* __restrict__ g2, const float* __restrict__ b2,
    const float* __restrict__ m2, const float* __restrict__ v2,
    float* __restrict__ Y, int s)
{
    __shared__ __align__(16) unsigned char SM[FU_SMEM];
    unsigned short (*Fin)[4][32] = (unsigned short (*)[4][32])SM;           // phase 1
    unsigned short (*As)[72]     = (unsigned short (*)[72])SM;              // phase 2 (union)
    unsigned short (*Bs)[64][72] = (unsigned short (*)[64][72])(SM + FU_OFF_BS);
    float* Wdw = (float*)(SM + FU_OFF_WDW);

    const int bx = blockIdx.x;            // n-tile (64 tokens = rows 2bx, 2bx+1)
    const int n0 = bx * 64;
    const int b  = blockIdx.y;
    const int t = threadIdx.x, wid = t >> 6, lane = t & 63;
    const int l16 = lane & 15, quad = lane >> 4;

    // ---- P0: stage Wdw + Fin (4 input rows x 128 c, bf16, with s>=2 residual add) ----
#pragma unroll
    for (int it = 0; it < 5; it++) {
        int idx = it * 256 + t;
        if (idx < 128 * 9) Wdw[idx] = w_dw[idx];
    }
    const float* src0 = Y_in + ((size_t)b * DIMM + s * CC) * NTOK;
    const float* src1 = Y_in + ((size_t)b * DIMM + (s - 1) * CC) * NTOK;
#pragma unroll
    for (int it = 0; it < 16; it++) {
        int flat = it * 256 + t;          // 4096 float4 chunks
        int c = flat >> 5, q = flat & 31;
        int n_in = n0 - 32 + q * 4;       // token index of this float4 (row = n_in>>5)
        float4 v = make_float4(0.f, 0.f, 0.f, 0.f);
        if ((unsigned)n_in < (unsigned)NTOK) {
            v = *(const float4*)&src0[(size_t)c * NTOK + n_in];
            if (s >= 2) {
                float4 u = *(const float4*)&src1[(size_t)c * NTOK + n_in];
                v.x += u.x; v.y += u.y; v.z += u.z; v.w += u.w;
            }
        }
        *(uint2*)&Fin[c][q >> 3][(q & 7) * 4] = make_uint2(f2bf2(v.x, v.y), f2bf2(v.z, v.w));
    }
    __syncthreads();

    // ---- P1: depthwise 3x3 -> Bs[n][c] (bf16). Wave handles 32 c (uniform), lane=(lr,col). ----
    {
        const int lr = lane >> 5, col = lane & 31;
#pragma unroll 4
        for (int cc = 0; cc < 32; cc++) {
            int c = wid * 32 + cc;
            const float* w = &Wdw[c * 9];
            float s0 = 0.f;
#pragma unroll
            for (int ky = 0; ky < 3; ky++) {
                int fr = lr + ky;
                float vm = 0.f, vp = 0.f;
                if (col > 0)  vm = bf2f(Fin[c][fr][col - 1]);
                float v0 = bf2f(Fin[c][fr][col]);
                if (col < 31) vp = bf2f(Fin[c][fr][col + 1]);
                s0 = fmaf(vm, w[ky * 3 + 0], s0);
                s0 = fmaf(v0, w[ky * 3 + 1], s0);
                s0 = fmaf(vp, w[ky * 3 + 2], s0);
            }
            Bs[c >> 6][lr * 32 + col][c & 63] = f2bf(s0);
        }
    }
    __syncthreads();

    // ---- P2: pw GEMM (K=128 in two halves; As staged into Fin region — Fin dead) ----
    const int wm = (wid >> 1) * 64, wn = (wid & 1) * 32;
    f32x4 acc[4][2];
#pragma unroll
    for (int i = 0; i < 4; i++) { acc[i][0] = (f32x4){0.f,0.f,0.f,0.f}; acc[i][1] = (f32x4){0.f,0.f,0.f,0.f}; }

    for (int k0 = 0; k0 < CC; k0 += 64) {
        __syncthreads();
#pragma unroll
        for (int it = 0; it < 8; it++) {
            int flat = it * 256 + t;
            int row = flat >> 4, c4 = flat & 15;
            float4 w4 = *(const float4*)&w_pw[(size_t)row * CC + k0 + c4 * 4];
            *(uint2*)&As[row][c4 * 4] = make_uint2(f2bf2(w4.x, w4.y), f2bf2(w4.z, w4.w));
        }
        __syncthreads();
        const int half = k0 >> 6;
#pragma unroll
        for (int kk = 0; kk < 2; kk++) {
            short8 af[4], bf_[2];
#pragma unroll
            for (int i = 0; i < 4; i++) af[i]  = *(const short8*)&As[wm + i * 16 + l16][kk * 32 + quad * 8];
#pragma unroll
            for (int j = 0; j < 2; j++) bf_[j] = *(const short8*)&Bs[half][wn + j * 16 + l16][kk * 32 + quad * 8];
#pragma unroll
            for (int i = 0; i < 4; i++)
#pragma unroll
                for (int j = 0; j < 2; j++)
                    acc[i][j] = __builtin_amdgcn_mfma_f32_16x16x32_bf16(af[i], bf_[j], acc[i][j], 0, 0, 0);
        }
    }
#pragma unroll
    for (int i = 0; i < 4; i++)
#pragma unroll
        for (int r = 0; r < 4; r++) {
            int o = wm + i * 16 + quad * 4 + r;
            float inv  = g2[o] / sqrtf(v2[o] + EPSB);
            float beta = b2[o] - m2[o] * inv;
#pragma unroll
            for (int j = 0; j < 2; j++) {
                int n = n0 + wn + j * 16 + l16;
                Y[((size_t)b * DIMM + s * CC + o) * NTOK + n] = acc[i][j][r] * inv + beta;
            }
        }
}

// ---------------- K3.5: prep — Y f32 -> Qt (token-major bf16) + Vp (PV A-frag order) ----------
__global__ __launch_bounds__(256) void k_prep(
    const float* __restrict__ Y,
    unsigned short* __restrict__ Vp,    // [128][8][8][64][8]
    unsigned short* __restrict__ Qt)    // [128][1024][32]
{
    __shared__ float T[32][129];
    const int jt = blockIdx.x;
    const int n0 = jt * 128;
    const int g  = blockIdx.y;
    const int b = g >> 4, s = (g >> 2) & 3, h = g & 3;
    const int cb = s * CC + h * DD;
    const int t = threadIdx.x;
#pragma unroll
    for (int k = 0; k < 8; k++) {
        int idx = k * 256 + t;
        int d = idx >> 6, jp = (idx & 63) * 2;
        float2 v = *(const float2*)&Y[((size_t)b * DIMM + cb + d) * NTOK + n0 + jp];
        T[d][jp] = v.x; T[d][jp + 1] = v.y;
    }
    __syncthreads();
#pragma unroll
    for (int k = 0; k < 8; k++) {
        int idx = k * 256 + t;
        int n = idx >> 4, dp = (idx & 15) * 2;
        *(unsigned int*)&Qt[((size_t)g * NTOK + n0 + n) * DD + dp] = f2bf2(T[dp][n], T[dp + 1][n]);
    }
#pragma unroll
    for (int e2 = 0; e2 < 2; e2++) {
        int e = e2 * 256 + t;
        int sub = e >> 6, lane = e & 63;
        int quad = lane >> 4, l16 = lane & 15;
        int d  = (sub & 1) * 16 + l16;
        int jb = (sub >> 1) * 32 + quad * 4;
        uint4 v;
        v.x = f2bf2(T[d][jb + 0],  T[d][jb + 1]);
        v.y = f2bf2(T[d][jb + 2],  T[d][jb + 3]);
        v.z = f2bf2(T[d][jb + 16], T[d][jb + 17]);
        v.w = f2bf2(T[d][jb + 18], T[d][jb + 19]);
        *(uint4*)&Vp[((((size_t)g * 8 + jt) * 8 + sub) * 64 + lane) * 8] = v;
    }
}

// ---------------- K4: register-only MFMA flash attention, fixed diag-shift, 2x qi ----------
__global__ __launch_bounds__(256) void k_attn(
    const unsigned short* __restrict__ Qtg,
    const unsigned short* __restrict__ Vp,
    unsigned short* __restrict__ Ob)
{
    const int blk = blockIdx.x;
    const int g = blk & 127, ib = blk >> 7;      // ib in 0..7 (128 qi per block)
    const int b = g >> 4;
    const int s = (g >> 2) & 3, h = g & 3;
    const int cb = s * CC + h * DD;
    const unsigned short* Qt = Qtg + (size_t)g * NTOK * DD;          // [token][d]
    const unsigned short* Vg = Vp + (size_t)g * 8 * 8 * 64 * 8;      // [jt][sub][lane][8]
    const int t = threadIdx.x;
    const int wid = t >> 6, lane = t & 63;
    const int l16 = lane & 15, quad = lane >> 4;
    const int i0 = ib * 128 + wid * 16 + l16;    // this lane's two token columns
    const int i1 = i0 + 64;

    const short8 qi0 = *(const short8*)&Qt[(size_t)i0 * DD + quad * 8];
    const short8 qi1 = *(const short8*)&Qt[(size_t)i1 * DD + quad * 8];
    const short8 ones = {0x3F80, 0x3F80, 0x3F80, 0x3F80, 0x3F80, 0x3F80, 0x3F80, 0x3F80};

    // m_est = q_i.q_i per column (valid shift since Q==K: rowmax >= diag; cancels in O/l)
    float dq0 = 0.f, dq1 = 0.f;
#pragma unroll
    for (int e = 0; e < 8; e++) {
        float v0 = __uint_as_float(((unsigned int)(unsigned short)qi0[e]) << 16);
        float v1 = __uint_as_float(((unsigned int)(unsigned short)qi1[e]) << 16);
        dq0 = fmaf(v0, v0, dq0);
        dq1 = fmaf(v1, v1, dq1);
    }
    dq0 += __shfl_xor(dq0, 16); dq0 += __shfl_xor(dq0, 32);
    dq1 += __shfl_xor(dq1, 16); dq1 += __shfl_xor(dq1, 32);
    const float mnk0 = dq0 * K2EXP;
    const float mnk1 = dq1 * K2EXP;

    f32x4 lacc0 = {0.f,0.f,0.f,0.f}, lacc1 = {0.f,0.f,0.f,0.f};
    f32x4 oacc0[2] = {{0.f,0.f,0.f,0.f},{0.f,0.f,0.f,0.f}};
    f32x4 oacc1[2] = {{0.f,0.f,0.f,0.f},{0.f,0.f,0.f,0.f}};
    const f32x4 zero4 = {0.f, 0.f, 0.f, 0.f};

#pragma unroll 2
    for (int jt = 0; jt < 8; jt++) {
        const int j0 = jt * TJ;
        short8 pb0[4], pb1[4];
        // per-jb: load qj once, 2 QK MFMAs, exp+pack immediately (sacc never lives as array)
#pragma unroll
        for (int jb = 0; jb < 8; jb++) {
            short8 qj = *(const short8*)&Qt[(size_t)(j0 + jb * 16 + l16) * DD + quad * 8];
            f32x4 s0 = __builtin_amdgcn_mfma_f32_16x16x32_bf16(qj, qi0, zero4, 0, 0, 0);
            f32x4 s1 = __builtin_amdgcn_mfma_f32_16x16x32_bf16(qj, qi1, zero4, 0, 0, 0);
            float a0 = __builtin_amdgcn_exp2f(fmaf(s0[0], K2EXP, -mnk0));
            float a1 = __builtin_amdgcn_exp2f(fmaf(s0[1], K2EXP, -mnk0));
            float a2 = __builtin_amdgcn_exp2f(fmaf(s0[2], K2EXP, -mnk0));
            float a3 = __builtin_amdgcn_exp2f(fmaf(s0[3], K2EXP, -mnk0));
            ((unsigned int*)&pb0[jb >> 1])[(jb & 1) * 2] =
                __builtin_amdgcn_perm(__float_as_uint(a1), __float_as_uint(a0), 0x07060302u);
            ((unsigned int*)&pb0[jb >> 1])[(jb & 1) * 2 + 1] =
                __builtin_amdgcn_perm(__float_as_uint(a3), __float_as_uint(a2), 0x07060302u);
            float c0 = __builtin_amdgcn_exp2f(fmaf(s1[0], K2EXP, -mnk1));
            float c1 = __builtin_amdgcn_exp2f(fmaf(s1[1], K2EXP, -mnk1));
            float c2 = __builtin_amdgcn_exp2f(fmaf(s1[2], K2EXP, -mnk1));
            float c3 = __builtin_amdgcn_exp2f(fmaf(s1[3], K2EXP, -mnk1));
            ((unsigned int*)&pb1[jb >> 1])[(jb & 1) * 2] =
                __builtin_amdgcn_perm(__float_as_uint(c1), __float_as_uint(c0), 0x07060302u);
            ((unsigned int*)&pb1[jb >> 1])[(jb & 1) * 2 + 1] =
                __builtin_amdgcn_perm(__float_as_uint(c3), __float_as_uint(c2), 0x07060302u);
        }

        // PV + row-sum MFMAs: each V fragment feeds BOTH qi columns
#pragma unroll
        for (int wp = 0; wp < 4; wp++) {
            short8 af0 = *(const short8*)&Vg[(((size_t)jt * 8 + wp * 2 + 0) * 64 + lane) * 8];
            short8 af1 = *(const short8*)&Vg[(((size_t)jt * 8 + wp * 2 + 1) * 64 + lane) * 8];
            oacc0[0] = __builtin_amdgcn_mfma_f32_16x16x32_bf16(af0, pb0[wp], oacc0[0], 0, 0, 0);
            oacc0[1] = __builtin_amdgcn_mfma_f32_16x16x32_bf16(af1, pb0[wp], oacc0[1], 0, 0, 0);
            lacc0    = __builtin_amdgcn_mfma_f32_16x16x32_bf16(ones, pb0[wp], lacc0, 0, 0, 0);
            oacc1[0] = __builtin_amdgcn_mfma_f32_16x16x32_bf16(af0, pb1[wp], oacc1[0], 0, 0, 0);
            oacc1[1] = __builtin_amdgcn_mfma_f32_16x16x32_bf16(af1, pb1[wp], oacc1[1], 0, 0, 0);
            lacc1    = __builtin_amdgcn_mfma_f32_16x16x32_bf16(ones, pb1[wp], lacc1, 0, 0, 0);
        }
    }

    // epilogue: oacc[dblk][r] = O^T[d][i]; l = lacc[0] (all rows of ones-MFMA D are equal)
    float invl0 = 1.f / lacc0[0];
    float invl1 = 1.f / lacc1[0];
#pragma unroll
    for (int dblk = 0; dblk < 2; dblk++) {
        uint2 pkd;
        pkd.x = f2bf2(oacc0[dblk][0] * invl0, oacc0[dblk][1] * invl0);
        pkd.y = f2bf2(oacc0[dblk][2] * invl0, oacc0[dblk][3] * invl0);
        *(uint2*)&Ob[((size_t)b * NTOK + i0) * DIMM + cb + dblk * 16 + quad * 4] = pkd;
        pkd.x = f2bf2(oacc1[dblk][0] * invl1, oacc1[dblk][1] * invl1);
        pkd.y = f2bf2(oacc1[dblk][2] * invl1, oacc1[dblk][3] * invl1);
        *(uint2*)&Ob[((size_t)b * NTOK + i1) * DIMM + cb + dblk * 16 + quad * 4] = pkd;
    }
}

// ---------------- K5: out-proj GEMM (A=Ob bf16 direct, B=w_out f32 inline-cvt), f32 out ----
__global__ __launch_bounds__(256) void k_mm_out(
    const unsigned short* __restrict__ Oin,  // [8192][512] bf16
    const float* __restrict__ w_out,         // [512][512] f32
    float* __restrict__ out)
{
    __shared__ __align__(16) unsigned short As[128][72];
    __shared__ __align__(16) unsigned short Bs[128][72];
    const int r0 = blockIdx.x * 128;
    const int o0 = blockIdx.y * 128;
    const int t = threadIdx.x, wid = t >> 6, lane = t & 63;
    const int l16 = lane & 15, quad = lane >> 4;
    const int wm = (wid >> 1) * 64, wn = (wid & 1) * 64;

    f32x4 acc[4][4];
#pragma unroll
    for (int i = 0; i < 4; i++)
#pragma unroll
        for (int j = 0; j < 4; j++) acc[i][j] = (f32x4){0.f, 0.f, 0.f, 0.f};

    for (int k0 = 0; k0 < DIMM; k0 += 64) {
        __syncthreads();
#pragma unroll
        for (int q = 0; q < 4; q++) {
            int flat = q * 256 + t;
            int row = flat >> 3, c8 = flat & 7;
            *(short8*)&As[row][c8 * 8] = *(const short8*)&Oin[(size_t)(r0 + row) * DIMM + k0 + c8 * 8];
        }
#pragma unroll
        for (int it = 0; it < 8; it++) {
            int flat = it * 256 + t;
            int row = flat >> 4, c4 = flat & 15;
            float4 w4 = *(const float4*)&w_out[(size_t)(o0 + row) * DIMM + k0 + c4 * 4];
            *(uint2*)&Bs[row][c4 * 4] = make_uint2(f2bf2(w4.x, w4.y), f2bf2(w4.z, w4.w));
        }
        __syncthreads();
#pragma unroll
        for (int kk = 0; kk < 2; kk++) {
            short8 af[4], bf_[4];
#pragma unroll
            for (int i = 0; i < 4; i++) af[i]  = *(const short8*)&As[wm + i * 16 + l16][kk * 32 + quad * 8];
#pragma unroll
            for (int j = 0; j < 4; j++) bf_[j] = *(const short8*)&Bs[wn + j * 16 + l16][kk * 32 + quad * 8];
#pragma unroll
            for (int i = 0; i < 4; i++)
#pragma unroll
                for (int j = 0; j < 4; j++)
                    acc[i][j] = __builtin_amdgcn_mfma_f32_16x16x32_bf16(af[i], bf_[j], acc[i][j], 0, 0, 0);
        }
    }
#pragma unroll
    for (int i = 0; i < 4; i++)
#pragma unroll
        for (int r = 0; r < 4; r++) {
            int rr = r0 + wm + i * 16 + quad * 4 + r;
#pragma unroll
            for (int j = 0; j < 4; j++) {
                int o = o0 + wn + j * 16 + l16;
                out[(size_t)rr * DIMM + o] = acc[i][j][r];
            }
        }
}

extern "C" void kernel_launch(void* const* d_in, const int* in_sizes, int n_in,
                              void* d_out, int out_size, void* d_ws, size_t ws_size,
                              hipStream_t stream)
{
    const float* x    = (const float*)d_in[0];
    const float* w_in = (const float*)d_in[1];
    const float* g1   = (const float*)d_in[2];
    const float* b1   = (const float*)d_in[3];
    const float* m1   = (const float*)d_in[4];
    const float* v1   = (const float*)d_in[5];
    const float* wdw  = (const float*)d_in[6];
    const float* wpw  = (const float*)d_in[7];
    const float* g2   = (const float*)d_in[8];
    const float* b2   = (const float*)d_in[9];
    const float* m2   = (const float*)d_in[10];
    const float* v2   = (const float*)d_in[11];
    const float* wout = (const float*)d_in[12];
    float* out = (float*)d_out;

    char* base = (char*)d_ws;
    float*          Y   = (float*)base;                                  // 16 MB (dies at prep)
    unsigned short* Ob  = (unsigned short*)base;                         // 8 MB  (attn out, over Y)
    unsigned short* Vp  = (unsigned short*)(base + (size_t)16 * 1024 * 1024); // 8 MB
    unsigned short* Qt  = (unsigned short*)(base + (size_t)24 * 1024 * 1024); // 8 MB

    k_mm_in<<<dim3(64, 4), 256, 0, stream>>>(w_in, x, g1, b1, m1, v1, Y);
    for (int s = 1; s <= 3; s++) {
        k_fused<<<dim3(16, 8), 256, 0, stream>>>(Y, wdw, wpw, g2, b2, m2, v2, Y, s);
    }
    k_prep<<<dim3(8, 128), 256, 0, stream>>>(Y, Vp, Qt);
    k_attn<<<dim3(1024), 256, 0, stream>>>(Qt, Vp, Ob);
    k_mm_out<<<dim3(64, 4), 256, 0, stream>>>(Ob, wout, out);
}

// Round 5
// 202.153 us; speedup vs baseline: 1.1507x; 1.1507x over previous
//
#include <hip/hip_runtime.h>
#include <hip/hip_bf16.h>

// MSAttention on MI355X. R15:
//  - REVERT R14 fusion (regressed 197->233: fused kernel ran dwconv at 128 blocks vs 1024,
//    half the CUs idle + slow scalar in-LDS conv). Back to R13's k_dwconv + k_mm_pw.
//  - k_attn: 4x qi amortization (was 2x in R13). Each lane owns FOUR query tokens
//    (i0, +64, +128, +192); every qj load feeds 4 QK MFMAs, every V fragment pair feeds 12
//    PV/lacc MFMAs. Grid 512. qj/V L2 traffic halves again (0.5 -> 0.25 GB), per-load ILP x2.
//  - R13 baseline: 197.1 us, absmax 0.150, k_attn ~37 us (latency-bound: MfmaUtil 12%,
//    VALUBusy 28%, HBM 4.7%, nothing saturated).
// ws layout (32 MB):
//   @0   Y   f32 [8][512][1024] 16 MB (mm_in -> convs -> prep)   then Ob bf16 [8192][512] 8 MB
//   @16  tmp f32 4 MB (convs)             then Vp bf16 [128][8jt][8sub][64lane][8] 8 MB (prep)
//   @24  Qt bf16 [128][1024][32] 8 MB (prep)

#define DIMM 512
#define NTOK 1024
#define CC   128
#define DD   32
#define BB   8
#define EPSB 1e-5f
#define SCALE_ATT 0.17677669529663687f   // 32^-0.5
#define K2EXP (SCALE_ATT * 1.4426950408889634f)  // scale * log2(e), folded into exp2
#define TJ 128

typedef __attribute__((ext_vector_type(8))) short short8;
typedef __attribute__((ext_vector_type(4))) float f32x4;

__device__ __forceinline__ unsigned short f2bf(float f) {
    unsigned int x = __float_as_uint(f);
    unsigned int r = x + 0x7fffu + ((x >> 16) & 1u);   // RNE, finite inputs
    return (unsigned short)(r >> 16);
}
__device__ __forceinline__ unsigned int f2bf2(float lo, float hi) {
    return (unsigned int)f2bf(lo) | ((unsigned int)f2bf(hi) << 16);
}

// ---------------- K1: inconv GEMM (MFMA bf16, inline f32->bf16 staging) + BN1 ----------------
__global__ __launch_bounds__(256) void k_mm_in(
    const float* __restrict__ w_in,   // [512][512]
    const float* __restrict__ x,      // [8192][512]
    const float* __restrict__ g1, const float* __restrict__ b1,
    const float* __restrict__ m1, const float* __restrict__ v1,
    float* __restrict__ Y)
{
    __shared__ __align__(16) unsigned short As[128][72];
    __shared__ __align__(16) unsigned short Bs[128][72];
    const int r0 = blockIdx.x * 128;
    const int o0 = blockIdx.y * 128;
    const int b  = r0 >> 10, nloc0 = r0 & 1023;
    const int t = threadIdx.x, wid = t >> 6, lane = t & 63;
    const int l16 = lane & 15, quad = lane >> 4;
    const int wm = (wid >> 1) * 64, wn = (wid & 1) * 64;

    f32x4 acc[4][4];
#pragma unroll
    for (int i = 0; i < 4; i++)
#pragma unroll
        for (int j = 0; j < 4; j++) acc[i][j] = (f32x4){0.f, 0.f, 0.f, 0.f};

    for (int k0 = 0; k0 < DIMM; k0 += 64) {
        __syncthreads();
#pragma unroll
        for (int it = 0; it < 8; it++) {
            int flat = it * 256 + t;
            int row = flat >> 4, c4 = flat & 15;
            float4 w4 = *(const float4*)&w_in[(size_t)(o0 + row) * DIMM + k0 + c4 * 4];
            *(uint2*)&As[row][c4 * 4] = make_uint2(f2bf2(w4.x, w4.y), f2bf2(w4.z, w4.w));
            float4 x4 = *(const float4*)&x[(size_t)(r0 + row) * DIMM + k0 + c4 * 4];
            *(uint2*)&Bs[row][c4 * 4] = make_uint2(f2bf2(x4.x, x4.y), f2bf2(x4.z, x4.w));
        }
        __syncthreads();
#pragma unroll
        for (int kk = 0; kk < 2; kk++) {
            short8 af[4], bf_[4];
#pragma unroll
            for (int i = 0; i < 4; i++) af[i]  = *(const short8*)&As[wm + i * 16 + l16][kk * 32 + quad * 8];
#pragma unroll
            for (int j = 0; j < 4; j++) bf_[j] = *(const short8*)&Bs[wn + j * 16 + l16][kk * 32 + quad * 8];
#pragma unroll
            for (int i = 0; i < 4; i++)
#pragma unroll
                for (int j = 0; j < 4; j++)
                    acc[i][j] = __builtin_amdgcn_mfma_f32_16x16x32_bf16(af[i], bf_[j], acc[i][j], 0, 0, 0);
        }
    }
#pragma unroll
    for (int i = 0; i < 4; i++)
#pragma unroll
        for (int r = 0; r < 4; r++) {
            int o = o0 + wm + i * 16 + quad * 4 + r;
            float inv  = g1[o] / sqrtf(v1[o] + EPSB);
            float beta = b1[o] - m1[o] * inv;
#pragma unroll
            for (int j = 0; j < 4; j++) {
                int n = nloc0 + wn + j * 16 + l16;
                Y[((size_t)b * DIMM + o) * NTOK + n] = acc[i][j][r] * inv + beta;
            }
        }
}

// ---------------- K2: depthwise 3x3 (R13 version) ----------------
__global__ __launch_bounds__(256) void k_dwconv(
    const float* __restrict__ Y, const float* __restrict__ w_dw,
    float* __restrict__ tmp, int s)
{
    __shared__ float img[34][34];
    const int c = blockIdx.x;
    const int b = blockIdx.y;
    const int t = threadIdx.x;
    for (int i = t; i < 34 * 34; i += 256) (&img[0][0])[i] = 0.f;
    __syncthreads();
    const float* src0 = Y + ((size_t)b * DIMM + s * CC + c) * NTOK;
    const float* src1 = (s >= 2) ? (Y + ((size_t)b * DIMM + (s - 1) * CC + c) * NTOK) : nullptr;
    for (int p = t; p < NTOK; p += 256) {
        float v = src0[p];
        if (src1) v += src1[p];
        img[(p >> 5) + 1][(p & 31) + 1] = v;
    }
    __syncthreads();
    float w[9];
#pragma unroll
    for (int i = 0; i < 9; i++) w[i] = w_dw[c * 9 + i];
    for (int p = t; p < NTOK; p += 256) {
        int yy = p >> 5, xx = p & 31;
        float s0 = 0.f;
#pragma unroll
        for (int ky = 0; ky < 3; ky++)
#pragma unroll
            for (int kx = 0; kx < 3; kx++)
                s0 += img[yy + ky][xx + kx] * w[ky * 3 + kx];
        tmp[((size_t)b * CC + c) * NTOK + p] = s0;
    }
}

// ---------------- K3: pointwise 1x1 via MFMA + BN2 (R13 version) ----------------
__global__ __launch_bounds__(256) void k_mm_pw(
    const float* __restrict__ tmp, const float* __restrict__ w_pw,
    const float* __restrict__ g2, const float* __restrict__ b2,
    const float* __restrict__ m2, const float* __restrict__ v2,
    float* __restrict__ Y, int s)
{
    __shared__ __align__(16) unsigned short As[128][72];  // [o][k]
    __shared__ __align__(16) unsigned short Bs[64][72];   // [n][k]
    const int n0 = blockIdx.x * 64;
    const int b  = blockIdx.y;
    const int t = threadIdx.x, wid = t >> 6, lane = t & 63;
    const int l16 = lane & 15, quad = lane >> 4;
    const int wm = (wid >> 1) * 64, wn = (wid & 1) * 32;

    f32x4 acc[4][2];
#pragma unroll
    for (int i = 0; i < 4; i++) { acc[i][0] = (f32x4){0.f,0.f,0.f,0.f}; acc[i][1] = (f32x4){0.f,0.f,0.f,0.f}; }

    for (int k0 = 0; k0 < CC; k0 += 64) {
        __syncthreads();
#pragma unroll
        for (int it = 0; it < 8; it++) {
            int flat = it * 256 + t;
            int row = flat >> 4, c4 = flat & 15;
            float4 w4 = *(const float4*)&w_pw[(size_t)row * CC + k0 + c4 * 4];
            *(uint2*)&As[row][c4 * 4] = make_uint2(f2bf2(w4.x, w4.y), f2bf2(w4.z, w4.w));
        }
#pragma unroll
        for (int it = 0; it < 4; it++) {
            int flat = it * 256 + t;
            int c = flat >> 4, n4 = (flat & 15) * 4;
            float4 v = *(const float4*)&tmp[((size_t)b * CC + k0 + c) * NTOK + n0 + n4];
            Bs[n4 + 0][c] = f2bf(v.x);
            Bs[n4 + 1][c] = f2bf(v.y);
            Bs[n4 + 2][c] = f2bf(v.z);
            Bs[n4 + 3][c] = f2bf(v.w);
        }
        __syncthreads();
#pragma unroll
        for (int kk = 0; kk < 2; kk++) {
            short8 af[4], bf_[2];
#pragma unroll
            for (int i = 0; i < 4; i++) af[i]  = *(const short8*)&As[wm + i * 16 + l16][kk * 32 + quad * 8];
#pragma unroll
            for (int j = 0; j < 2; j++) bf_[j] = *(const short8*)&Bs[wn + j * 16 + l16][kk * 32 + quad * 8];
#pragma unroll
            for (int i = 0; i < 4; i++)
#pragma unroll
                for (int j = 0; j < 2; j++)
                    acc[i][j] = __builtin_amdgcn_mfma_f32_16x16x32_bf16(af[i], bf_[j], acc[i][j], 0, 0, 0);
        }
    }
#pragma unroll
    for (int i = 0; i < 4; i++)
#pragma unroll
        for (int r = 0; r < 4; r++) {
            int o = wm + i * 16 + quad * 4 + r;
            float inv  = g2[o] / sqrtf(v2[o] + EPSB);
            float beta = b2[o] - m2[o] * inv;
#pragma unroll
            for (int j = 0; j < 2; j++) {
                int n = n0 + wn + j * 16 + l16;
                Y[((size_t)b * DIMM + s * CC + o) * NTOK + n] = acc[i][j][r] * inv + beta;
            }
        }
}

// ---------------- K3.5: prep — Y f32 -> Qt (token-major bf16) + Vp (PV A-frag order) ----------
__global__ __launch_bounds__(256) void k_prep(
    const float* __restrict__ Y,
    unsigned short* __restrict__ Vp,    // [128][8][8][64][8]
    unsigned short* __restrict__ Qt)    // [128][1024][32]
{
    __shared__ float T[32][129];
    const int jt = blockIdx.x;
    const int n0 = jt * 128;
    const int g  = blockIdx.y;
    const int b = g >> 4, s = (g >> 2) & 3, h = g & 3;
    const int cb = s * CC + h * DD;
    const int t = threadIdx.x;
#pragma unroll
    for (int k = 0; k < 8; k++) {
        int idx = k * 256 + t;
        int d = idx >> 6, jp = (idx & 63) * 2;
        float2 v = *(const float2*)&Y[((size_t)b * DIMM + cb + d) * NTOK + n0 + jp];
        T[d][jp] = v.x; T[d][jp + 1] = v.y;
    }
    __syncthreads();
#pragma unroll
    for (int k = 0; k < 8; k++) {
        int idx = k * 256 + t;
        int n = idx >> 4, dp = (idx & 15) * 2;
        *(unsigned int*)&Qt[((size_t)g * NTOK + n0 + n) * DD + dp] = f2bf2(T[dp][n], T[dp + 1][n]);
    }
#pragma unroll
    for (int e2 = 0; e2 < 2; e2++) {
        int e = e2 * 256 + t;
        int sub = e >> 6, lane = e & 63;
        int quad = lane >> 4, l16 = lane & 15;
        int d  = (sub & 1) * 16 + l16;
        int jb = (sub >> 1) * 32 + quad * 4;
        uint4 v;
        v.x = f2bf2(T[d][jb + 0],  T[d][jb + 1]);
        v.y = f2bf2(T[d][jb + 2],  T[d][jb + 3]);
        v.z = f2bf2(T[d][jb + 16], T[d][jb + 17]);
        v.w = f2bf2(T[d][jb + 18], T[d][jb + 19]);
        *(uint4*)&Vp[((((size_t)g * 8 + jt) * 8 + sub) * 64 + lane) * 8] = v;
    }
}

// ---------------- K4: register-only MFMA flash attention, fixed diag-shift, 4x qi ----------
__global__ __launch_bounds__(256) void k_attn(
    const unsigned short* __restrict__ Qtg,
    const unsigned short* __restrict__ Vp,
    unsigned short* __restrict__ Ob)
{
    const int blk = blockIdx.x;
    const int g = blk & 127, ib = blk >> 7;      // ib in 0..3 (256 qi per block)
    const int b = g >> 4;
    const int s = (g >> 2) & 3, h = g & 3;
    const int cb = s * CC + h * DD;
    const unsigned short* Qt = Qtg + (size_t)g * NTOK * DD;          // [token][d]
    const unsigned short* Vg = Vp + (size_t)g * 8 * 8 * 64 * 8;      // [jt][sub][lane][8]
    const int t = threadIdx.x;
    const int wid = t >> 6, lane = t & 63;
    const int l16 = lane & 15, quad = lane >> 4;
    const int ibase = ib * 256 + wid * 16 + l16;  // this lane's four token columns: +64*c

    short8 qi[4];
#pragma unroll
    for (int c = 0; c < 4; c++)
        qi[c] = *(const short8*)&Qt[(size_t)(ibase + c * 64) * DD + quad * 8];
    const short8 ones = {0x3F80, 0x3F80, 0x3F80, 0x3F80, 0x3F80, 0x3F80, 0x3F80, 0x3F80};

    // m_est = q_i.q_i per column (valid shift since Q==K: rowmax >= diag; cancels in O/l)
    float mnk[4];
#pragma unroll
    for (int c = 0; c < 4; c++) {
        float dq = 0.f;
#pragma unroll
        for (int e = 0; e < 8; e++) {
            float v = __uint_as_float(((unsigned int)(unsigned short)qi[c][e]) << 16);
            dq = fmaf(v, v, dq);
        }
        dq += __shfl_xor(dq, 16);
        dq += __shfl_xor(dq, 32);
        mnk[c] = dq * K2EXP;
    }

    f32x4 lacc[4];
    f32x4 oacc[4][2];
#pragma unroll
    for (int c = 0; c < 4; c++) {
        lacc[c] = (f32x4){0.f,0.f,0.f,0.f};
        oacc[c][0] = (f32x4){0.f,0.f,0.f,0.f};
        oacc[c][1] = (f32x4){0.f,0.f,0.f,0.f};
    }
    const f32x4 zero4 = {0.f, 0.f, 0.f, 0.f};

    for (int jt = 0; jt < 8; jt++) {
        const int j0 = jt * TJ;
        short8 pb[4][4];   // [col][wp]
        // per-jb: load qj once, 4 QK MFMAs, exp+pack immediately
#pragma unroll
        for (int jb = 0; jb < 8; jb++) {
            short8 qj = *(const short8*)&Qt[(size_t)(j0 + jb * 16 + l16) * DD + quad * 8];
#pragma unroll
            for (int c = 0; c < 4; c++) {
                f32x4 sc = __builtin_amdgcn_mfma_f32_16x16x32_bf16(qj, qi[c], zero4, 0, 0, 0);
                float p0 = __builtin_amdgcn_exp2f(fmaf(sc[0], K2EXP, -mnk[c]));
                float p1 = __builtin_amdgcn_exp2f(fmaf(sc[1], K2EXP, -mnk[c]));
                float p2 = __builtin_amdgcn_exp2f(fmaf(sc[2], K2EXP, -mnk[c]));
                float p3 = __builtin_amdgcn_exp2f(fmaf(sc[3], K2EXP, -mnk[c]));
                ((unsigned int*)&pb[c][jb >> 1])[(jb & 1) * 2] =
                    __builtin_amdgcn_perm(__float_as_uint(p1), __float_as_uint(p0), 0x07060302u);
                ((unsigned int*)&pb[c][jb >> 1])[(jb & 1) * 2 + 1] =
                    __builtin_amdgcn_perm(__float_as_uint(p3), __float_as_uint(p2), 0x07060302u);
            }
        }

        // PV + row-sum MFMAs: each V fragment pair feeds all 4 qi columns
#pragma unroll
        for (int wp = 0; wp < 4; wp++) {
            short8 af0 = *(const short8*)&Vg[(((size_t)jt * 8 + wp * 2 + 0) * 64 + lane) * 8];
            short8 af1 = *(const short8*)&Vg[(((size_t)jt * 8 + wp * 2 + 1) * 64 + lane) * 8];
#pragma unroll
            for (int c = 0; c < 4; c++) {
                oacc[c][0] = __builtin_amdgcn_mfma_f32_16x16x32_bf16(af0, pb[c][wp], oacc[c][0], 0, 0, 0);
                oacc[c][1] = __builtin_amdgcn_mfma_f32_16x16x32_bf16(af1, pb[c][wp], oacc[c][1], 0, 0, 0);
                lacc[c]    = __builtin_amdgcn_mfma_f32_16x16x32_bf16(ones, pb[c][wp], lacc[c], 0, 0, 0);
            }
        }
    }

    // epilogue: oacc[c][dblk][r] = O^T[d][i_c]; l = lacc[c][0] (all rows of ones-MFMA D equal)
#pragma unroll
    for (int c = 0; c < 4; c++) {
        float invl = 1.f / lacc[c][0];
        const int i = ibase + c * 64;
#pragma unroll
        for (int dblk = 0; dblk < 2; dblk++) {
            uint2 pkd;
            pkd.x = f2bf2(oacc[c][dblk][0] * invl, oacc[c][dblk][1] * invl);
            pkd.y = f2bf2(oacc[c][dblk][2] * invl, oacc[c][dblk][3] * invl);
            *(uint2*)&Ob[((size_t)b * NTOK + i) * DIMM + cb + dblk * 16 + quad * 4] = pkd;
        }
    }
}

// ---------------- K5: out-proj GEMM (A=Ob bf16 direct, B=w_out f32 inline-cvt), f32 out ----
__global__ __launch_bounds__(256) void k_mm_out(
    const unsigned short* __restrict__ Oin,  // [8192][512] bf16
    const float* __restrict__ w_out,         // [512][512] f32
    float* __restrict__ out)
{
    __shared__ __align__(16) unsigned short As[128][72];
    __shared__ __align__(16) unsigned short Bs[128][72];
    const int r0 = blockIdx.x * 128;
    const int o0 = blockIdx.y * 128;
    const int t = threadIdx.x, wid = t >> 6, lane = t & 63;
    const int l16 = lane & 15, quad = lane >> 4;
    const int wm = (wid >> 1) * 64, wn = (wid & 1) * 64;

    f32x4 acc[4][4];
#pragma unroll
    for (int i = 0; i < 4; i++)
#pragma unroll
        for (int j = 0; j < 4; j++) acc[i][j] = (f32x4){0.f, 0.f, 0.f, 0.f};

    for (int k0 = 0; k0 < DIMM; k0 += 64) {
        __syncthreads();
#pragma unroll
        for (int q = 0; q < 4; q++) {
            int flat = q * 256 + t;
            int row = flat >> 3, c8 = flat & 7;
            *(short8*)&As[row][c8 * 8] = *(const short8*)&Oin[(size_t)(r0 + row) * DIMM + k0 + c8 * 8];
        }
#pragma unroll
        for (int it = 0; it < 8; it++) {
            int flat = it * 256 + t;
            int row = flat >> 4, c4 = flat & 15;
            float4 w4 = *(const float4*)&w_out[(size_t)(o0 + row) * DIMM + k0 + c4 * 4];
            *(uint2*)&Bs[row][c4 * 4] = make_uint2(f2bf2(w4.x, w4.y), f2bf2(w4.z, w4.w));
        }
        __syncthreads();
#pragma unroll
        for (int kk = 0; kk < 2; kk++) {
            short8 af[4], bf_[4];
#pragma unroll
            for (int i = 0; i < 4; i++) af[i]  = *(const short8*)&As[wm + i * 16 + l16][kk * 32 + quad * 8];
#pragma unroll
            for (int j = 0; j < 4; j++) bf_[j] = *(const short8*)&Bs[wn + j * 16 + l16][kk * 32 + quad * 8];
#pragma unroll
            for (int i = 0; i < 4; i++)
#pragma unroll
                for (int j = 0; j < 4; j++)
                    acc[i][j] = __builtin_amdgcn_mfma_f32_16x16x32_bf16(af[i], bf_[j], acc[i][j], 0, 0, 0);
        }
    }
#pragma unroll
    for (int i = 0; i < 4; i++)
#pragma unroll
        for (int r = 0; r < 4; r++) {
            int rr = r0 + wm + i * 16 + quad * 4 + r;
#pragma unroll
            for (int j = 0; j < 4; j++) {
                int o = o0 + wn + j * 16 + l16;
                out[(size_t)rr * DIMM + o] = acc[i][j][r];
            }
        }
}

extern "C" void kernel_launch(void* const* d_in, const int* in_sizes, int n_in,
                              void* d_out, int out_size, void* d_ws, size_t ws_size,
                              hipStream_t stream)
{
    const float* x    = (const float*)d_in[0];
    const float* w_in = (const float*)d_in[1];
    const float* g1   = (const float*)d_in[2];
    const float* b1   = (const float*)d_in[3];
    const float* m1   = (const float*)d_in[4];
    const float* v1   = (const float*)d_in[5];
    const float* wdw  = (const float*)d_in[6];
    const float* wpw  = (const float*)d_in[7];
    const float* g2   = (const float*)d_in[8];
    const float* b2   = (const float*)d_in[9];
    const float* m2   = (const float*)d_in[10];
    const float* v2   = (const float*)d_in[11];
    const float* wout = (const float*)d_in[12];
    float* out = (float*)d_out;

    char* base = (char*)d_ws;
    float*          Y   = (float*)base;                                  // 16 MB (dies at prep)
    unsigned short* Ob  = (unsigned short*)base;                         // 8 MB  (attn out, over Y)
    float*          tmp = (float*)(base + (size_t)16 * 1024 * 1024);     // 4 MB  (convs)
    unsigned short* Vp  = (unsigned short*)(base + (size_t)16 * 1024 * 1024); // 8 MB (after tmp dies)
    unsigned short* Qt  = (unsigned short*)(base + (size_t)24 * 1024 * 1024); // 8 MB

    k_mm_in<<<dim3(64, 4), 256, 0, stream>>>(w_in, x, g1, b1, m1, v1, Y);
    for (int s = 1; s <= 3; s++) {
        k_dwconv<<<dim3(CC, BB), 256, 0, stream>>>(Y, wdw, tmp, s);
        k_mm_pw<<<dim3(16, 8), 256, 0, stream>>>(tmp, wpw, g2, b2, m2, v2, Y, s);
    }
    k_prep<<<dim3(8, 128), 256, 0, stream>>>(Y, Vp, Qt);
    k_attn<<<dim3(512), 256, 0, stream>>>(Qt, Vp, Ob);
    k_mm_out<<<dim3(64, 4), 256, 0, stream>>>(Ob, wout, out);
}

// Round 6
// 194.224 us; speedup vs baseline: 1.1977x; 1.0408x over previous
//
#include <hip/hip_runtime.h>
#include <hip/hip_bf16.h>

// MSAttention on MI355X. R16:
//  - k_attn: revert to R13's 2x-qi structure (R15's 4x regressed: VGPR/occupancy trade).
//  - k_attn: LDS-stage the shared K-tile (8KB) + V-tile (8KB) per block, double-buffered via
//    global_load_lds(width16) issued BEFORE the compute phase (latency hides under MFMA+exp).
//    The 4 waves previously each re-read identical 16KB/tile from L2 (64KB/block/tile).
//    K-tile uses a 4-slot XOR swizzle applied on the GLOBAL SOURCE side (gl_lds writes linearly);
//    slot constants fold to lane-invariants. V staging is linear (frags already per-lane).
//  - everything else identical to R13 (197.1 us) / R15 (202.2 us, absmax 0.150).
// ws layout (32 MB):
//   @0   Y   f32 [8][512][1024] 16 MB (mm_in -> convs -> prep)   then Ob bf16 [8192][512] 8 MB
//   @16  tmp f32 4 MB (convs)             then Vp bf16 [128][8jt][8sub][64lane][8] 8 MB (prep)
//   @24  Qt bf16 [128][1024][32] 8 MB (prep)

#define DIMM 512
#define NTOK 1024
#define CC   128
#define DD   32
#define BB   8
#define EPSB 1e-5f
#define SCALE_ATT 0.17677669529663687f   // 32^-0.5
#define K2EXP (SCALE_ATT * 1.4426950408889634f)  // scale * log2(e), folded into exp2
#define TJ 128

typedef __attribute__((ext_vector_type(8))) short short8;
typedef __attribute__((ext_vector_type(4))) float f32x4;

__device__ __forceinline__ unsigned short f2bf(float f) {
    unsigned int x = __float_as_uint(f);
    unsigned int r = x + 0x7fffu + ((x >> 16) & 1u);   // RNE, finite inputs
    return (unsigned short)(r >> 16);
}
__device__ __forceinline__ unsigned int f2bf2(float lo, float hi) {
    return (unsigned int)f2bf(lo) | ((unsigned int)f2bf(hi) << 16);
}
__device__ __forceinline__ void gl_lds16(const void* g, void* l) {
    __builtin_amdgcn_global_load_lds(
        (const __attribute__((address_space(1))) unsigned int*)g,
        (__attribute__((address_space(3))) unsigned int*)l, 16, 0, 0);
}

// ---------------- K1: inconv GEMM (MFMA bf16, inline f32->bf16 staging) + BN1 ----------------
__global__ __launch_bounds__(256) void k_mm_in(
    const float* __restrict__ w_in,   // [512][512]
    const float* __restrict__ x,      // [8192][512]
    const float* __restrict__ g1, const float* __restrict__ b1,
    const float* __restrict__ m1, const float* __restrict__ v1,
    float* __restrict__ Y)
{
    __shared__ __align__(16) unsigned short As[128][72];
    __shared__ __align__(16) unsigned short Bs[128][72];
    const int r0 = blockIdx.x * 128;
    const int o0 = blockIdx.y * 128;
    const int b  = r0 >> 10, nloc0 = r0 & 1023;
    const int t = threadIdx.x, wid = t >> 6, lane = t & 63;
    const int l16 = lane & 15, quad = lane >> 4;
    const int wm = (wid >> 1) * 64, wn = (wid & 1) * 64;

    f32x4 acc[4][4];
#pragma unroll
    for (int i = 0; i < 4; i++)
#pragma unroll
        for (int j = 0; j < 4; j++) acc[i][j] = (f32x4){0.f, 0.f, 0.f, 0.f};

    for (int k0 = 0; k0 < DIMM; k0 += 64) {
        __syncthreads();
#pragma unroll
        for (int it = 0; it < 8; it++) {
            int flat = it * 256 + t;
            int row = flat >> 4, c4 = flat & 15;
            float4 w4 = *(const float4*)&w_in[(size_t)(o0 + row) * DIMM + k0 + c4 * 4];
            *(uint2*)&As[row][c4 * 4] = make_uint2(f2bf2(w4.x, w4.y), f2bf2(w4.z, w4.w));
            float4 x4 = *(const float4*)&x[(size_t)(r0 + row) * DIMM + k0 + c4 * 4];
            *(uint2*)&Bs[row][c4 * 4] = make_uint2(f2bf2(x4.x, x4.y), f2bf2(x4.z, x4.w));
        }
        __syncthreads();
#pragma unroll
        for (int kk = 0; kk < 2; kk++) {
            short8 af[4], bf_[4];
#pragma unroll
            for (int i = 0; i < 4; i++) af[i]  = *(const short8*)&As[wm + i * 16 + l16][kk * 32 + quad * 8];
#pragma unroll
            for (int j = 0; j < 4; j++) bf_[j] = *(const short8*)&Bs[wn + j * 16 + l16][kk * 32 + quad * 8];
#pragma unroll
            for (int i = 0; i < 4; i++)
#pragma unroll
                for (int j = 0; j < 4; j++)
                    acc[i][j] = __builtin_amdgcn_mfma_f32_16x16x32_bf16(af[i], bf_[j], acc[i][j], 0, 0, 0);
        }
    }
#pragma unroll
    for (int i = 0; i < 4; i++)
#pragma unroll
        for (int r = 0; r < 4; r++) {
            int o = o0 + wm + i * 16 + quad * 4 + r;
            float inv  = g1[o] / sqrtf(v1[o] + EPSB);
            float beta = b1[o] - m1[o] * inv;
#pragma unroll
            for (int j = 0; j < 4; j++) {
                int n = nloc0 + wn + j * 16 + l16;
                Y[((size_t)b * DIMM + o) * NTOK + n] = acc[i][j][r] * inv + beta;
            }
        }
}

// ---------------- K2: depthwise 3x3 (R13 version) ----------------
__global__ __launch_bounds__(256) void k_dwconv(
    const float* __restrict__ Y, const float* __restrict__ w_dw,
    float* __restrict__ tmp, int s)
{
    __shared__ float img[34][34];
    const int c = blockIdx.x;
    const int b = blockIdx.y;
    const int t = threadIdx.x;
    for (int i = t; i < 34 * 34; i += 256) (&img[0][0])[i] = 0.f;
    __syncthreads();
    const float* src0 = Y + ((size_t)b * DIMM + s * CC + c) * NTOK;
    const float* src1 = (s >= 2) ? (Y + ((size_t)b * DIMM + (s - 1) * CC + c) * NTOK) : nullptr;
    for (int p = t; p < NTOK; p += 256) {
        float v = src0[p];
        if (src1) v += src1[p];
        img[(p >> 5) + 1][(p & 31) + 1] = v;
    }
    __syncthreads();
    float w[9];
#pragma unroll
    for (int i = 0; i < 9; i++) w[i] = w_dw[c * 9 + i];
    for (int p = t; p < NTOK; p += 256) {
        int yy = p >> 5, xx = p & 31;
        float s0 = 0.f;
#pragma unroll
        for (int ky = 0; ky < 3; ky++)
#pragma unroll
            for (int kx = 0; kx < 3; kx++)
                s0 += img[yy + ky][xx + kx] * w[ky * 3 + kx];
        tmp[((size_t)b * CC + c) * NTOK + p] = s0;
    }
}

// ---------------- K3: pointwise 1x1 via MFMA + BN2 (R13 version) ----------------
__global__ __launch_bounds__(256) void k_mm_pw(
    const float* __restrict__ tmp, const float* __restrict__ w_pw,
    const float* __restrict__ g2, const float* __restrict__ b2,
    const float* __restrict__ m2, const float* __restrict__ v2,
    float* __restrict__ Y, int s)
{
    __shared__ __align__(16) unsigned short As[128][72];  // [o][k]
    __shared__ __align__(16) unsigned short Bs[64][72];   // [n][k]
    const int n0 = blockIdx.x * 64;
    const int b  = blockIdx.y;
    const int t = threadIdx.x, wid = t >> 6, lane = t & 63;
    const int l16 = lane & 15, quad = lane >> 4;
    const int wm = (wid >> 1) * 64, wn = (wid & 1) * 32;

    f32x4 acc[4][2];
#pragma unroll
    for (int i = 0; i < 4; i++) { acc[i][0] = (f32x4){0.f,0.f,0.f,0.f}; acc[i][1] = (f32x4){0.f,0.f,0.f,0.f}; }

    for (int k0 = 0; k0 < CC; k0 += 64) {
        __syncthreads();
#pragma unroll
        for (int it = 0; it < 8; it++) {
            int flat = it * 256 + t;
            int row = flat >> 4, c4 = flat & 15;
            float4 w4 = *(const float4*)&w_pw[(size_t)row * CC + k0 + c4 * 4];
            *(uint2*)&As[row][c4 * 4] = make_uint2(f2bf2(w4.x, w4.y), f2bf2(w4.z, w4.w));
        }
#pragma unroll
        for (int it = 0; it < 4; it++) {
            int flat = it * 256 + t;
            int c = flat >> 4, n4 = (flat & 15) * 4;
            float4 v = *(const float4*)&tmp[((size_t)b * CC + k0 + c) * NTOK + n0 + n4];
            Bs[n4 + 0][c] = f2bf(v.x);
            Bs[n4 + 1][c] = f2bf(v.y);
            Bs[n4 + 2][c] = f2bf(v.z);
            Bs[n4 + 3][c] = f2bf(v.w);
        }
        __syncthreads();
#pragma unroll
        for (int kk = 0; kk < 2; kk++) {
            short8 af[4], bf_[2];
#pragma unroll
            for (int i = 0; i < 4; i++) af[i]  = *(const short8*)&As[wm + i * 16 + l16][kk * 32 + quad * 8];
#pragma unroll
            for (int j = 0; j < 2; j++) bf_[j] = *(const short8*)&Bs[wn + j * 16 + l16][kk * 32 + quad * 8];
#pragma unroll
            for (int i = 0; i < 4; i++)
#pragma unroll
                for (int j = 0; j < 2; j++)
                    acc[i][j] = __builtin_amdgcn_mfma_f32_16x16x32_bf16(af[i], bf_[j], acc[i][j], 0, 0, 0);
        }
    }
#pragma unroll
    for (int i = 0; i < 4; i++)
#pragma unroll
        for (int r = 0; r < 4; r++) {
            int o = wm + i * 16 + quad * 4 + r;
            float inv  = g2[o] / sqrtf(v2[o] + EPSB);
            float beta = b2[o] - m2[o] * inv;
#pragma unroll
            for (int j = 0; j < 2; j++) {
                int n = n0 + wn + j * 16 + l16;
                Y[((size_t)b * DIMM + s * CC + o) * NTOK + n] = acc[i][j][r] * inv + beta;
            }
        }
}

// ---------------- K3.5: prep — Y f32 -> Qt (token-major bf16) + Vp (PV A-frag order) ----------
__global__ __launch_bounds__(256) void k_prep(
    const float* __restrict__ Y,
    unsigned short* __restrict__ Vp,    // [128][8][8][64][8]
    unsigned short* __restrict__ Qt)    // [128][1024][32]
{
    __shared__ float T[32][129];
    const int jt = blockIdx.x;
    const int n0 = jt * 128;
    const int g  = blockIdx.y;
    const int b = g >> 4, s = (g >> 2) & 3, h = g & 3;
    const int cb = s * CC + h * DD;
    const int t = threadIdx.x;
#pragma unroll
    for (int k = 0; k < 8; k++) {
        int idx = k * 256 + t;
        int d = idx >> 6, jp = (idx & 63) * 2;
        float2 v = *(const float2*)&Y[((size_t)b * DIMM + cb + d) * NTOK + n0 + jp];
        T[d][jp] = v.x; T[d][jp + 1] = v.y;
    }
    __syncthreads();
#pragma unroll
    for (int k = 0; k < 8; k++) {
        int idx = k * 256 + t;
        int n = idx >> 4, dp = (idx & 15) * 2;
        *(unsigned int*)&Qt[((size_t)g * NTOK + n0 + n) * DD + dp] = f2bf2(T[dp][n], T[dp + 1][n]);
    }
#pragma unroll
    for (int e2 = 0; e2 < 2; e2++) {
        int e = e2 * 256 + t;
        int sub = e >> 6, lane = e & 63;
        int quad = lane >> 4, l16 = lane & 15;
        int d  = (sub & 1) * 16 + l16;
        int jb = (sub >> 1) * 32 + quad * 4;
        uint4 v;
        v.x = f2bf2(T[d][jb + 0],  T[d][jb + 1]);
        v.y = f2bf2(T[d][jb + 2],  T[d][jb + 3]);
        v.z = f2bf2(T[d][jb + 16], T[d][jb + 17]);
        v.w = f2bf2(T[d][jb + 18], T[d][jb + 19]);
        *(uint4*)&Vp[((((size_t)g * 8 + jt) * 8 + sub) * 64 + lane) * 8] = v;
    }
}

// ---------------- K4: MFMA flash attention, fixed diag-shift, 2x qi, LDS-staged K/V ----------
__global__ __launch_bounds__(256) void k_attn(
    const unsigned short* __restrict__ Qtg,
    const unsigned short* __restrict__ Vp,
    unsigned short* __restrict__ Ob)
{
    __shared__ __align__(16) unsigned short Kt[2][128][32];   // 8KB x2, swizzled 16B slots
    __shared__ __align__(16) unsigned short Vt[2][8][64][8];  // 8KB x2, linear frag order

    const int blk = blockIdx.x;
    const int g = blk & 127, ib = blk >> 7;      // ib in 0..7 (128 qi per block)
    const int b = g >> 4;
    const int s = (g >> 2) & 3, h = g & 3;
    const int cb = s * CC + h * DD;
    const unsigned short* Qt = Qtg + (size_t)g * NTOK * DD;          // [token][d]
    const unsigned short* Vg = Vp + (size_t)g * 8 * 8 * 64 * 8;      // [jt][sub][lane][8]
    const int t = threadIdx.x;
    const int wid = t >> 6, lane = t & 63;
    const int l16 = lane & 15, quad = lane >> 4;
    const int i0 = ib * 128 + wid * 16 + l16;    // this lane's two token columns
    const int i1 = i0 + 64;

    const short8 qi0 = *(const short8*)&Qt[(size_t)i0 * DD + quad * 8];
    const short8 qi1 = *(const short8*)&Qt[(size_t)i1 * DD + quad * 8];
    const short8 ones = {0x3F80, 0x3F80, 0x3F80, 0x3F80, 0x3F80, 0x3F80, 0x3F80, 0x3F80};

    // staging lane-constants. K stage: lane covers (row = base + lane>>2, slot = lane&3);
    // global col = (slot ^ ((row>>1)&3))*8 = (slot ^ ((lane>>3)&3))*8 (lane-invariant form).
    const int krow_l = lane >> 2;
    const int kgcol  = ((lane & 3) ^ ((lane >> 3) & 3)) * 8;
    // read-side swizzled slot: quad ^ ((row>>1)&3) with row = jb*16+l16 -> quad ^ ((l16>>1)&3)
    const int kswz = (quad ^ ((l16 >> 1) & 3)) * 8;

    // m_est = q_i.q_i per column (valid shift since Q==K: rowmax >= diag; cancels in O/l)
    float dq0 = 0.f, dq1 = 0.f;
#pragma unroll
    for (int e = 0; e < 8; e++) {
        float v0 = __uint_as_float(((unsigned int)(unsigned short)qi0[e]) << 16);
        float v1 = __uint_as_float(((unsigned int)(unsigned short)qi1[e]) << 16);
        dq0 = fmaf(v0, v0, dq0);
        dq1 = fmaf(v1, v1, dq1);
    }
    dq0 += __shfl_xor(dq0, 16); dq0 += __shfl_xor(dq0, 32);
    dq1 += __shfl_xor(dq1, 16); dq1 += __shfl_xor(dq1, 32);
    const float mnk0 = dq0 * K2EXP;
    const float mnk1 = dq1 * K2EXP;

    f32x4 lacc0 = {0.f,0.f,0.f,0.f}, lacc1 = {0.f,0.f,0.f,0.f};
    f32x4 oacc0[2] = {{0.f,0.f,0.f,0.f},{0.f,0.f,0.f,0.f}};
    f32x4 oacc1[2] = {{0.f,0.f,0.f,0.f},{0.f,0.f,0.f,0.f}};
    const f32x4 zero4 = {0.f, 0.f, 0.f, 0.f};

    // stage tile jt_ into buffer bsel: each wave stages its 32 K-rows (2 calls) + 2 V-subs.
    auto stage = [&](int bsel, int jt_) {
#pragma unroll
        for (int c = 0; c < 2; c++) {
            int grow = jt_ * TJ + wid * 32 + c * 16 + krow_l;
            gl_lds16(&Qt[(size_t)grow * DD + kgcol], &Kt[bsel][wid * 32 + c * 16][0]);
        }
#pragma unroll
        for (int c = 0; c < 2; c++) {
            int sub = wid * 2 + c;
            gl_lds16(&Vg[(((size_t)jt_ * 8 + sub) * 64 + lane) * 8], &Vt[bsel][sub][0][0]);
        }
    };

    stage(0, 0);
    __syncthreads();   // drains vmcnt: buffer 0 ready

    for (int jt = 0; jt < 8; jt++) {
        const int cur = jt & 1;
        if (jt < 7) stage(cur ^ 1, jt + 1);   // async into other buffer, lands by next barrier

        short8 pb0[4], pb1[4];
#pragma unroll
        for (int jb = 0; jb < 8; jb++) {
            short8 qj = *(const short8*)&Kt[cur][jb * 16 + l16][kswz];
            f32x4 s0 = __builtin_amdgcn_mfma_f32_16x16x32_bf16(qj, qi0, zero4, 0, 0, 0);
            f32x4 s1 = __builtin_amdgcn_mfma_f32_16x16x32_bf16(qj, qi1, zero4, 0, 0, 0);
            float a0 = __builtin_amdgcn_exp2f(fmaf(s0[0], K2EXP, -mnk0));
            float a1 = __builtin_amdgcn_exp2f(fmaf(s0[1], K2EXP, -mnk0));
            float a2 = __builtin_amdgcn_exp2f(fmaf(s0[2], K2EXP, -mnk0));
            float a3 = __builtin_amdgcn_exp2f(fmaf(s0[3], K2EXP, -mnk0));
            ((unsigned int*)&pb0[jb >> 1])[(jb & 1) * 2] =
                __builtin_amdgcn_perm(__float_as_uint(a1), __float_as_uint(a0), 0x07060302u);
            ((unsigned int*)&pb0[jb >> 1])[(jb & 1) * 2 + 1] =
                __builtin_amdgcn_perm(__float_as_uint(a3), __float_as_uint(a2), 0x07060302u);
            float c0 = __builtin_amdgcn_exp2f(fmaf(s1[0], K2EXP, -mnk1));
            float c1 = __builtin_amdgcn_exp2f(fmaf(s1[1], K2EXP, -mnk1));
            float c2 = __builtin_amdgcn_exp2f(fmaf(s1[2], K2EXP, -mnk1));
            float c3 = __builtin_amdgcn_exp2f(fmaf(s1[3], K2EXP, -mnk1));
            ((unsigned int*)&pb1[jb >> 1])[(jb & 1) * 2] =
                __builtin_amdgcn_perm(__float_as_uint(c1), __float_as_uint(c0), 0x07060302u);
            ((unsigned int*)&pb1[jb >> 1])[(jb & 1) * 2 + 1] =
                __builtin_amdgcn_perm(__float_as_uint(c3), __float_as_uint(c2), 0x07060302u);
        }

        // PV + row-sum MFMAs from LDS V fragments (each feeds BOTH qi columns)
#pragma unroll
        for (int wp = 0; wp < 4; wp++) {
            short8 af0 = *(const short8*)&Vt[cur][wp * 2 + 0][lane][0];
            short8 af1 = *(const short8*)&Vt[cur][wp * 2 + 1][lane][0];
            oacc0[0] = __builtin_amdgcn_mfma_f32_16x16x32_bf16(af0, pb0[wp], oacc0[0], 0, 0, 0);
            oacc0[1] = __builtin_amdgcn_mfma_f32_16x16x32_bf16(af1, pb0[wp], oacc0[1], 0, 0, 0);
            lacc0    = __builtin_amdgcn_mfma_f32_16x16x32_bf16(ones, pb0[wp], lacc0, 0, 0, 0);
            oacc1[0] = __builtin_amdgcn_mfma_f32_16x16x32_bf16(af0, pb1[wp], oacc1[0], 0, 0, 0);
            oacc1[1] = __builtin_amdgcn_mfma_f32_16x16x32_bf16(af1, pb1[wp], oacc1[1], 0, 0, 0);
            lacc1    = __builtin_amdgcn_mfma_f32_16x16x32_bf16(ones, pb1[wp], lacc1, 0, 0, 0);
        }

        __syncthreads();   // all waves done with cur; next buffer's loads drained
    }

    // epilogue: oacc[dblk][r] = O^T[d][i]; l = lacc[0] (all rows of ones-MFMA D are equal)
    float invl0 = 1.f / lacc0[0];
    float invl1 = 1.f / lacc1[0];
#pragma unroll
    for (int dblk = 0; dblk < 2; dblk++) {
        uint2 pkd;
        pkd.x = f2bf2(oacc0[dblk][0] * invl0, oacc0[dblk][1] * invl0);
        pkd.y = f2bf2(oacc0[dblk][2] * invl0, oacc0[dblk][3] * invl0);
        *(uint2*)&Ob[((size_t)b * NTOK + i0) * DIMM + cb + dblk * 16 + quad * 4] = pkd;
        pkd.x = f2bf2(oacc1[dblk][0] * invl1, oacc1[dblk][1] * invl1);
        pkd.y = f2bf2(oacc1[dblk][2] * invl1, oacc1[dblk][3] * invl1);
        *(uint2*)&Ob[((size_t)b * NTOK + i1) * DIMM + cb + dblk * 16 + quad * 4] = pkd;
    }
}

// ---------------- K5: out-proj GEMM (A=Ob bf16 direct, B=w_out f32 inline-cvt), f32 out ----
__global__ __launch_bounds__(256) void k_mm_out(
    const unsigned short* __restrict__ Oin,  // [8192][512] bf16
    const float* __restrict__ w_out,         // [512][512] f32
    float* __restrict__ out)
{
    __shared__ __align__(16) unsigned short As[128][72];
    __shared__ __align__(16) unsigned short Bs[128][72];
    const int r0 = blockIdx.x * 128;
    const int o0 = blockIdx.y * 128;
    const int t = threadIdx.x, wid = t >> 6, lane = t & 63;
    const int l16 = lane & 15, quad = lane >> 4;
    const int wm = (wid >> 1) * 64, wn = (wid & 1) * 64;

    f32x4 acc[4][4];
#pragma unroll
    for (int i = 0; i < 4; i++)
#pragma unroll
        for (int j = 0; j < 4; j++) acc[i][j] = (f32x4){0.f, 0.f, 0.f, 0.f};

    for (int k0 = 0; k0 < DIMM; k0 += 64) {
        __syncthreads();
#pragma unroll
        for (int q = 0; q < 4; q++) {
            int flat = q * 256 + t;
            int row = flat >> 3, c8 = flat & 7;
            *(short8*)&As[row][c8 * 8] = *(const short8*)&Oin[(size_t)(r0 + row) * DIMM + k0 + c8 * 8];
        }
#pragma unroll
        for (int it = 0; it < 8; it++) {
            int flat = it * 256 + t;
            int row = flat >> 4, c4 = flat & 15;
            float4 w4 = *(const float4*)&w_out[(size_t)(o0 + row) * DIMM + k0 + c4 * 4];
            *(uint2*)&Bs[row][c4 * 4] = make_uint2(f2bf2(w4.x, w4.y), f2bf2(w4.z, w4.w));
        }
        __syncthreads();
#pragma unroll
        for (int kk = 0; kk < 2; kk++) {
            short8 af[4], bf_[4];
#pragma unroll
            for (int i = 0; i < 4; i++) af[i]  = *(const short8*)&As[wm + i * 16 + l16][kk * 32 + quad * 8];
#pragma unroll
            for (int j = 0; j < 4; j++) bf_[j] = *(const short8*)&Bs[wn + j * 16 + l16][kk * 32 + quad * 8];
#pragma unroll
            for (int i = 0; i < 4; i++)
#pragma unroll
                for (int j = 0; j < 4; j++)
                    acc[i][j] = __builtin_amdgcn_mfma_f32_16x16x32_bf16(af[i], bf_[j], acc[i][j], 0, 0, 0);
        }
    }
#pragma unroll
    for (int i = 0; i < 4; i++)
#pragma unroll
        for (int r = 0; r < 4; r++) {
            int rr = r0 + wm + i * 16 + quad * 4 + r;
#pragma unroll
            for (int j = 0; j < 4; j++) {
                int o = o0 + wn + j * 16 + l16;
                out[(size_t)rr * DIMM + o] = acc[i][j][r];
            }
        }
}

extern "C" void kernel_launch(void* const* d_in, const int* in_sizes, int n_in,
                              void* d_out, int out_size, void* d_ws, size_t ws_size,
                              hipStream_t stream)
{
    const float* x    = (const float*)d_in[0];
    const float* w_in = (const float*)d_in[1];
    const float* g1   = (const float*)d_in[2];
    const float* b1   = (const float*)d_in[3];
    const float* m1   = (const float*)d_in[4];
    const float* v1   = (const float*)d_in[5];
    const float* wdw  = (const float*)d_in[6];
    const float* wpw  = (const float*)d_in[7];
    const float* g2   = (const float*)d_in[8];
    const float* b2   = (const float*)d_in[9];
    const float* m2   = (const float*)d_in[10];
    const float* v2   = (const float*)d_in[11];
    const float* wout = (const float*)d_in[12];
    float* out = (float*)d_out;

    char* base = (char*)d_ws;
    float*          Y   = (float*)base;                                  // 16 MB (dies at prep)
    unsigned short* Ob  = (unsigned short*)base;                         // 8 MB  (attn out, over Y)
    float*          tmp = (float*)(base + (size_t)16 * 1024 * 1024);     // 4 MB  (convs)
    unsigned short* Vp  = (unsigned short*)(base + (size_t)16 * 1024 * 1024); // 8 MB (after tmp dies)
    unsigned short* Qt  = (unsigned short*)(base + (size_t)24 * 1024 * 1024); // 8 MB

    k_mm_in<<<dim3(64, 4), 256, 0, stream>>>(w_in, x, g1, b1, m1, v1, Y);
    for (int s = 1; s <= 3; s++) {
        k_dwconv<<<dim3(CC, BB), 256, 0, stream>>>(Y, wdw, tmp, s);
        k_mm_pw<<<dim3(16, 8), 256, 0, stream>>>(tmp, wpw, g2, b2, m2, v2, Y, s);
    }
    k_prep<<<dim3(8, 128), 256, 0, stream>>>(Y, Vp, Qt);
    k_attn<<<dim3(1024), 256, 0, stream>>>(Qt, Vp, Ob);
    k_mm_out<<<dim3(64, 4), 256, 0, stream>>>(Ob, wout, out);
}